// Round 4
// baseline (484.665 us; speedup 1.0000x reference)
//
#include <hip/hip_runtime.h>
#include <hip/hip_fp16.h>

// B=16 E=128 W=256 HID=64 HOR=12; row = b*128+e (2048 rows).
// Key algebraic facts exploited:
//  (1) softmax row sums to 1 => at most ONE adj_soft entry > 0.5 per row =>
//      adj_bin is one-hot-or-empty => GAT softmax is exactly one-hot (or
//      uniform when fully masked) => h_temp[i] = gr[j*] or mean_j gr[j],
//      E_coup = E[j*] or 0. No logits, no gl, no 128x128 work in the scan.
//  (2) cnn telescopes: h(t)[p] = G[t+4p], G precomputable for s<253.
//  (3) gr(t) = grPre(t) (parallel precompute, fp16) + <=3 corrections from
//      sequential G values (p in {61,62,63}).
// 4 launches, no cooperative launch (harness rejects it - measured twice).

struct Params {
  const float *__restrict__ x, *__restrict__ noise, *__restrict__ aw, *__restrict__ ab,
              *__restrict__ pe_w1, *__restrict__ pe_b1, *__restrict__ bn_g, *__restrict__ bn_b,
              *__restrict__ bn_m, *__restrict__ bn_v, *__restrict__ pe_w2, *__restrict__ pe_b2,
              *__restrict__ w1, *__restrict__ b1, *__restrict__ w2, *__restrict__ b2,
              *__restrict__ w3, *__restrict__ b3, *__restrict__ wl, *__restrict__ bl,
              *__restrict__ wr, *__restrict__ br, *__restrict__ attn, *__restrict__ out_w,
              *__restrict__ out_b, *__restrict__ ce_w, *__restrict__ ce_b, *__restrict__ cd_w,
              *__restrict__ cd_b, *__restrict__ q_w, *__restrict__ q_b, *__restrict__ k_w,
              *__restrict__ k_b;
  float* ws;
  float* out;
};

__device__ __forceinline__ float fast_tanh(float x) {
  float t = exp2f(fminf(2.8853900818f * x, 126.0f));   // exp(2x)
  return 1.0f - 2.0f * __builtin_amdgcn_rcpf(t + 1.0f);
}
__device__ __forceinline__ float fast_sigmoid(float x) {
  float t = exp2f(fminf(-1.44269504f * x, 126.0f));
  return __builtin_amdgcn_rcpf(1.0f + t);
}
__device__ __forceinline__ float wsum(float v) {
  #pragma unroll
  for (int m = 1; m < 64; m <<= 1) v += __shfl_xor(v, m, 64);
  return v;
}
__device__ __forceinline__ float wmax(float v) {
  #pragma unroll
  for (int m = 1; m < 64; m <<= 1) v = fmaxf(v, __shfl_xor(v, m, 64));
  return v;
}

// workspace layout (float offsets), total ~5.97 MB (proven-safe: round-2 used 7.97)
#define OFF_XW   0        // 2048*256 xf window  (DEAD after k3g; overlaid by grPre)
#define OFF_GRP  0        // fp16 grPre: 12*2048*64 halves = 786432 floats
#define OFF_G    786432   // G: 2048*256 (s<253 valid)
#define OFF_QV   1310720  // 2048*32
#define OFF_KV   1376256  // 2048*32
#define OFF_XT   1441792  // xtail: 2048*24  (cols 248..271 of window)
#define OFF_JS   1490944  // jstar: 2048 ints
#define OFF_MS   1492992  // mean[16], std[16]

// ---------- k2x: fused mean/std + conv5+bn+relu + conv1x1 + affine -> xw ----------
// grid 2048 (block=(b,e)), 256 threads (thread=w). Redundant per-block reduce.
__global__ __launch_bounds__(256)
void k2x(Params P) {
  __shared__ float red[8];
  const int tid = threadIdx.x, blk = blockIdx.x;
  const int b = blk >> 7, e = blk & 127, w = tid;
  const int lane = tid & 63, wv = tid >> 6;

  float v = P.x[b * 256 + w];
  float s = wsum(v), s2 = wsum(v * v);
  if (lane == 0) { red[wv] = s; red[4 + wv] = s2; }
  __syncthreads();
  float st  = red[0] + red[1] + red[2] + red[3];
  float st2 = red[4] + red[5] + red[6] + red[7];
  float mean = st * (1.f / 256.f);
  float var  = st2 * (1.f / 256.f) - mean * mean;
  float sd   = sqrtf(var);
  if (e == 0 && tid == 0) { P.ws[OFF_MS + b] = mean; P.ws[OFF_MS + 16 + b] = sd; }
  float rstd = 1.f / sd;

  float xv[5];
  #pragma unroll
  for (int k = 0; k < 5; k++) {
    int u = w - 2 + k;
    xv[k] = (u >= 0 && u < 256) ? (P.x[b * 256 + u] - mean) * rstd : 0.f;
  }
  float acc = P.pe_b2[e];
  #pragma unroll 4
  for (int c = 0; c < 32; c++) {
    float a = P.pe_b1[c];
    #pragma unroll
    for (int k = 0; k < 5; k++) a += P.pe_w1[c * 5 + k] * xv[k];
    a = fmaxf(a, 0.f);
    float sc = P.bn_g[c] / sqrtf(P.bn_v[c] + 1e-5f);
    float h0 = (a - P.bn_m[c]) * sc + P.bn_b[c];
    acc += P.pe_w2[e * 32 + c] * h0;
  }
  acc = acc * P.aw[e] + P.ab[e];
  P.ws[OFF_XW + blk * 256 + w] = acc;
}

// ---------- k3g: per-row G (telescoped CNN) + q/k projection + xtail ----------
// grid 2048 (block=row), 256 threads.
__global__ __launch_bounds__(256)
void k3g(Params P) {
  __shared__ float xrow[256];
  __shared__ float pp[256];
  const int tid = threadIdx.x;
  const int row = blockIdx.x;
  const int e = row & 127;
  float* ws = P.ws;

  xrow[tid] = ws[OFF_XW + row * 256 + tid];
  __syncthreads();
  if (tid < 8) ws[OFF_XT + row * 24 + tid] = xrow[248 + tid];

  // CNN: thread = s
  const int s = tid;
  if (s < 253) {
    const float* w1p = P.w1 + e * 128;
    const float* w2p = P.w2 + e * 512;
    const float* w3p = P.w3 + e * 64;
    const float* b1p = P.b1 + e * 64;
    const float* b2p = P.b2 + e * 64;
    float X0 = xrow[s], X1 = xrow[s + 1], X2 = xrow[s + 2], X3 = xrow[s + 3];
    float acc = 0.f;
    #pragma unroll 1
    for (int g2 = 0; g2 < 16; g2++) {
      float h1v[8];
      #pragma unroll
      for (int ic = 0; ic < 4; ic++) {
        int ch = g2 * 4 + ic;
        float ww0 = w1p[ch * 2], ww1 = w1p[ch * 2 + 1], bb = b1p[ch];
        h1v[ic * 2 + 0] = fast_tanh(bb + ww0 * X0 + ww1 * X1);
        h1v[ic * 2 + 1] = fast_tanh(bb + ww0 * X2 + ww1 * X3);
      }
      #pragma unroll
      for (int oc = 0; oc < 4; oc++) {
        int ch = g2 * 4 + oc;
        const float* wq = w2p + ch * 8;
        float a2 = b2p[ch];
        #pragma unroll
        for (int u = 0; u < 8; u++) a2 += wq[u] * h1v[u];
        acc += w3p[ch] * fast_tanh(a2);
      }
    }
    ws[OFF_G + row * 256 + s] = fast_tanh(P.b3[e] + acc);
  }

  // q/k: unit u = tid>>2 (u<32: q[h=u], else k[h=u-32]); c = tid&3 quarter of dot
  {
    const int u = tid >> 2, c = tid & 3;
    const int h = u & 31;
    const float* wm = (u < 32) ? P.q_w : P.k_w;
    const float* wp = wm + h * 256 + c * 64;
    const float* xp = xrow + c * 64;
    float acc = 0.f;
    #pragma unroll 4
    for (int i = 0; i < 64; i += 4) {
      float4 a = *(const float4*)(xp + i);
      float4 wq = *(const float4*)(wp + i);
      acc += a.x * wq.x + a.y * wq.y + a.z * wq.z + a.w * wq.w;
    }
    pp[tid] = acc;
  }
  __syncthreads();
  if (tid < 64) {
    float r = pp[tid * 4] + pp[tid * 4 + 1] + pp[tid * 4 + 2] + pp[tid * 4 + 3];
    if (tid < 32) ws[OFF_QV + row * 32 + tid] = r + P.q_b[tid];
    else          ws[OFF_KV + row * 32 + tid - 32] = r + P.k_b[tid - 32];
  }
}

// ---------- kmid: blocks<512: adjacency softmax + jstar; blocks>=512: grPre ----------
__global__ __launch_bounds__(256)
void kmid(Params P) {
  __shared__ float pool[272];
  const int tid = threadIdx.x, blk = blockIdx.x;
  float* ws = P.ws;

  if (blk < 512) {
    // adjacency: one wave per row (identical math to the round-2 PASS)
    const int lane = tid & 63, wv = tid >> 6;
    const int row = blk * 4 + wv;
    const int b = row >> 7;
    float* hb = pool + wv * 64;   // 32 used
    if (lane < 32) hb[lane] = ws[OFF_QV + row * 32 + lane];
    __syncthreads();
    float ev0, ev1;
    #pragma unroll
    for (int half = 0; half < 2; half++) {
      int j = lane + half * 64;
      const float* kr = ws + OFF_KV + (b * 128 + j) * 32;
      float acc = 0.f;
      #pragma unroll
      for (int h = 0; h < 32; h += 4) {
        float4 kk = *(const float4*)(kr + h);
        float4 qq = *(const float4*)(hb + h);
        acc += qq.x * kk.x + qq.y * kk.y + qq.z * kk.z + qq.w * kk.w;
      }
      if (half == 0) ev0 = acc; else ev1 = acc;
    }
    float m   = wmax(fmaxf(ev0, ev1));
    float p0  = __expf(ev0 - m), p1 = __expf(ev1 - m);
    float inv = 1.f / wsum(p0 + p1);
    float a0 = p0 * inv, a1 = p1 * inv;
    P.out[38912 + row * 128 + lane]      = a0;
    P.out[38912 + row * 128 + lane + 64] = a1;
    unsigned long long m0 = __ballot(a0 > 0.5f);
    unsigned long long m1 = __ballot(a1 > 0.5f);
    if (lane == 0) {
      int js = m0 ? (int)__builtin_ctzll(m0) : (m1 ? 64 + (int)__builtin_ctzll(m1) : -1);
      ((int*)(ws + OFF_JS))[row] = js;
    }
  } else {
    // grPre[t][row][o] = br[o] + sum_{p: t+4p<253} G[row][t+4p] * wr[o][p]   (fp16)
    const int row = blk - 512;
    float* GS = pool;
    if (tid < 253) GS[tid] = ws[OFF_G + row * 256 + tid];
    __syncthreads();
    __half* gph = (__half*)(ws + OFF_GRP);
    const int o = tid & 63, tg = tid >> 6;
    #pragma unroll
    for (int k = 0; k < 3; k++) {
      int t = tg * 3 + k;
      int pmax = (256 - t) >> 2;
      const float* wro = P.wr + o * 64;
      float acc = P.br[o];
      for (int p = 0; p < pmax; p++) acc += GS[t + 4 * p] * wro[p];
      gph[((size_t)t * 2048 + row) * 64 + o] = __float2half(acc);
    }
  }
}

// ---------- kscan: 16 blocks (block=b) x 1024 threads; whole 12-step scan in-block ----------
__global__ __launch_bounds__(1024, 1)
void kscan(Params P) {
  __shared__ float hfT[64 * 133];        // hf transposed [f][row], pad 133
  __shared__ float GlateS[12 * 128];     // G[row][253+t'] values
  __shared__ float QS[2 * 3 * 128];      // double-buffered Q state
  __shared__ float meanPreS[12 * 64];
  __shared__ float xtS[128 * 24];        // window tail, cols 248.. (idx = s-248)
  __shared__ float WrS[3 * 64];          // wr[o][p] for p=61,62,63 -> WrS[p-61][o]
  __shared__ int   jstarS[128];
  __shared__ float xpS[128];
  __shared__ float GsumS[16];

  const int tid = threadIdx.x, lane = tid & 63, wv = tid >> 6;
  const int b = blockIdx.x;
  float* ws = P.ws;
  const __half* gph = (const __half*)(ws + OFF_GRP);
  const float* Gg = ws + OFF_G;

  // ---- setup ----
  for (int i = tid; i < 1536; i += 1024) GlateS[i] = 0.f;
  if (tid < 16) GsumS[tid] = 0.f;
  if (tid < 128) {
    jstarS[tid] = ((const int*)(ws + OFF_JS))[b * 128 + tid];
    QS[0 * 384 + 0 + tid] = 1.f; QS[0 * 384 + 128 + tid] = 0.f; QS[0 * 384 + 256 + tid] = 0.f;
  }
  if (tid < 192) WrS[tid] = P.wr[(tid & 63) * 64 + 61 + (tid >> 6)];
  for (int i = tid; i < 3072; i += 1024) xtS[i] = ws[OFF_XT + b * 3072 + i];
  if (tid < 768) {
    int t = tid >> 6, o = tid & 63;
    float sm = 0.f;
    for (int j = 0; j < 128; j++)
      sm += __half2float(gph[((size_t)t * 2048 + b * 128 + j) * 64 + o]);
    meanPreS[tid] = sm * (1.f / 128.f);
  }
  __syncthreads();

  const float meanb = ws[OFF_MS + b], stdb = ws[OFF_MS + 16 + b];

  for (int t = 0; t < 12; t++) {
    const int par = t & 1, parn = par ^ 1;

    // ---- V1: hf per row (lane=f), xp via wave reduce ----
    #pragma unroll 1
    for (int r = 0; r < 8; r++) {
      const int rowL = wv * 8 + r;
      const int row = b * 128 + rowL, e = rowL;
      const int jj = jstarS[rowL];
      float ht;
      if (jj >= 0) {
        ht = __half2float(gph[((size_t)t * 2048 + b * 128 + jj) * 64 + lane]);
        if (t >= 1) ht += GlateS[(t - 1) * 128 + jj] * WrS[128 + lane];  // p=63
        if (t >= 5) ht += GlateS[(t - 5) * 128 + jj] * WrS[64 + lane];   // p=62
        if (t >= 9) ht += GlateS[(t - 9) * 128 + jj] * WrS[lane];        // p=61
      } else {
        ht = meanPreS[t * 64 + lane];
        if (t >= 1) ht += GsumS[t - 1] * (1.f / 128.f) * WrS[128 + lane];
        if (t >= 5) ht += GsumS[t - 5] * (1.f / 128.f) * WrS[64 + lane];
        if (t >= 9) ht += GsumS[t - 9] * (1.f / 128.f) * WrS[lane];
      }
      float th = fast_tanh(ht);
      int s0 = t + 4 * lane;
      float ho = (s0 < 253) ? Gg[row * 256 + s0] : GlateS[(s0 - 253) * 128 + rowL];
      float q0 = QS[par * 384 + rowL], q1 = QS[par * 384 + 128 + rowL], q2 = QS[par * 384 + 256 + rowL];
      float hc = fast_tanh(P.ce_b[lane] + q0 * P.ce_w[lane * 3] + q1 * P.ce_w[lane * 3 + 1]
                           + q2 * P.ce_w[lane * 3 + 2]);
      float hf = ho + th + hc;
      hfT[lane * 133 + rowL] = hf;
      float xp = wsum(hf * P.out_w[e * 64 + lane]) + P.out_b[e];
      if (lane == 0) xpS[rowL] = xp;
    }
    __syncthreads();

    // ---- S1: per-row scalar chain (lane = row; waves 0,1) ----
    if (wv < 2) {
      const int rowL = wv * 64 + lane;
      const int row = b * 128 + rowL, e = rowL;
      float d0 = 0.f, d1 = 0.f, d2 = 0.f, d3 = 0.f;
      #pragma unroll 8
      for (int f = 0; f < 64; f++) {
        float h = hfT[f * 133 + rowL];
        d0 += h * P.cd_w[f];
        d1 += h * P.cd_w[64 + f];
        d2 += h * P.cd_w[128 + f];
        d3 += h * P.cd_w[192 + f];
      }
      float al = fast_sigmoid(d0 + P.cd_b[0]);
      float be = fast_sigmoid(d1 + P.cd_b[1]);
      float ga = fast_sigmoid(d2 + P.cd_b[2]);
      float et = fast_sigmoid(d3 + P.cd_b[3]);
      float q0 = QS[par * 384 + rowL], q1 = QS[par * 384 + 128 + rowL], q2 = QS[par * 384 + 256 + rowL];
      int jj = jstarS[rowL];
      float Ec = (jj >= 0) ? QS[par * 384 + 128 + jj] : 0.f;
      float nz = P.noise[t * 2048 + row];
      float Hn = q0 - al * q0;
      float En = q1 + be * q0 - ga * q1 + 0.1f * Ec;
      float Vn = q2 + et * q1 + nz * 0.01f;
      QS[parn * 384 + rowL] = Hn;
      QS[parn * 384 + 128 + rowL] = En;
      QS[parn * 384 + 256 + rowL] = Vn;
      float xp = xpS[rowL];
      P.out[row * 12 + t] = (xp - P.ab[e]) / P.aw[e] * stdb + meanb;
      if (t == 11) {
        P.out[24576 + row * 3] = Hn; P.out[24576 + row * 3 + 1] = En; P.out[24576 + row * 3 + 2] = Vn;
        P.out[30720 + row * 4] = al; P.out[30720 + row * 4 + 1] = be;
        P.out[30720 + row * 4 + 2] = ga; P.out[30720 + row * 4 + 3] = et;
      }
    }
    __syncthreads();

    // ---- V2: incremental CNN column (lane = channel) ----
    if (t < 11) {
      #pragma unroll 1
      for (int r = 0; r < 8; r++) {
        const int rowL = wv * 8 + r;
        const int e = rowL;
        const float* xb = xtS + rowL * 24;
        float X0 = xb[5 + t], X1 = xb[6 + t], X2 = xb[7 + t];
        float X3 = xpS[rowL];
        float2 w1v = ((const float2*)(P.w1 + e * 128))[lane];
        float b1v = P.b1[e * 64 + lane];
        float h1a = fast_tanh(b1v + w1v.x * X0 + w1v.y * X1);
        float h1c = fast_tanh(b1v + w1v.x * X2 + w1v.y * X3);
        int src = (lane >> 2) * 4;
        float4 wlo = *(const float4*)(P.w2 + e * 512 + lane * 8);
        float4 whi = *(const float4*)(P.w2 + e * 512 + lane * 8 + 4);
        float a2 = P.b2[e * 64 + lane];
        a2 += wlo.x * __shfl(h1a, src + 0, 64) + wlo.y * __shfl(h1c, src + 0, 64);
        a2 += wlo.z * __shfl(h1a, src + 1, 64) + wlo.w * __shfl(h1c, src + 1, 64);
        a2 += whi.x * __shfl(h1a, src + 2, 64) + whi.y * __shfl(h1c, src + 2, 64);
        a2 += whi.z * __shfl(h1a, src + 3, 64) + whi.w * __shfl(h1c, src + 3, 64);
        float h2 = fast_tanh(a2);
        float g3 = wsum(P.w3[e * 64 + lane] * h2);
        float Gn = fast_tanh(P.b3[e] + g3);
        if (lane == 0) {
          GlateS[t * 128 + rowL] = Gn;
          atomicAdd(&GsumS[t], Gn);
          xtS[rowL * 24 + 8 + t] = X3;
        }
      }
    }
    __syncthreads();
  }
}

extern "C" void kernel_launch(void* const* d_in, const int* in_sizes, int n_in,
                              void* d_out, int out_size, void* d_ws, size_t ws_size,
                              hipStream_t stream) {
  Params p;
  p.x     = (const float*)d_in[0];  p.noise = (const float*)d_in[1];
  p.aw    = (const float*)d_in[2];  p.ab    = (const float*)d_in[3];
  p.pe_w1 = (const float*)d_in[4];  p.pe_b1 = (const float*)d_in[5];
  p.bn_g  = (const float*)d_in[6];  p.bn_b  = (const float*)d_in[7];
  p.bn_m  = (const float*)d_in[8];  p.bn_v  = (const float*)d_in[9];
  p.pe_w2 = (const float*)d_in[10]; p.pe_b2 = (const float*)d_in[11];
  p.w1    = (const float*)d_in[12]; p.b1    = (const float*)d_in[13];
  p.w2    = (const float*)d_in[14]; p.b2    = (const float*)d_in[15];
  p.w3    = (const float*)d_in[16]; p.b3    = (const float*)d_in[17];
  p.wl    = (const float*)d_in[18]; p.bl    = (const float*)d_in[19];
  p.wr    = (const float*)d_in[20]; p.br    = (const float*)d_in[21];
  p.attn  = (const float*)d_in[22]; p.out_w = (const float*)d_in[23];
  p.out_b = (const float*)d_in[24]; p.ce_w  = (const float*)d_in[25];
  p.ce_b  = (const float*)d_in[26]; p.cd_w  = (const float*)d_in[27];
  p.cd_b  = (const float*)d_in[28]; p.q_w   = (const float*)d_in[29];
  p.q_b   = (const float*)d_in[30]; p.k_w   = (const float*)d_in[31];
  p.k_b   = (const float*)d_in[32];
  p.ws  = (float*)d_ws;
  p.out = (float*)d_out;

  k2x  <<<dim3(2048), dim3(256),  0, stream>>>(p);
  k3g  <<<dim3(2048), dim3(256),  0, stream>>>(p);
  kmid <<<dim3(2560), dim3(256),  0, stream>>>(p);
  kscan<<<dim3(16),   dim3(1024), 0, stream>>>(p);
}